// Round 6
// baseline (119.856 us; speedup 1.0000x reference)
//
#include <hip/hip_runtime.h>
#include <hip/hip_bf16.h>

typedef __attribute__((ext_vector_type(4))) float f32x4;
typedef __attribute__((ext_vector_type(8))) short bf16x8;

#define M_TOT 30752   // 8*62*62 output pixels

__device__ __forceinline__ unsigned short f2bf(float f) {
  unsigned int u = __float_as_uint(f);
  u = u + 0x7FFF + ((u >> 16) & 1);   // round-to-nearest-even
  return (unsigned short)(u >> 16);
}

__device__ __forceinline__ void gload16(const void* g, void* l) {
  __builtin_amdgcn_global_load_lds((const __attribute__((address_space(1))) unsigned int*)g,
                                   (__attribute__((address_space(3))) unsigned int*)l,
                                   16, 0, 0);
}

// ---- prep 1: cast x (fp32) -> bf16, 8 elems/thread ----
__global__ void cast_x(const float* __restrict__ x, unsigned short* __restrict__ xb) {
  int i = blockIdx.x * 256 + threadIdx.x;
  const f32x4* xp = (const f32x4*)x;
  f32x4 a = xp[2 * i];
  f32x4 b = xp[2 * i + 1];
  bf16x8 o;
  o[0] = (short)f2bf(a[0]); o[1] = (short)f2bf(a[1]);
  o[2] = (short)f2bf(a[2]); o[3] = (short)f2bf(a[3]);
  o[4] = (short)f2bf(b[0]); o[5] = (short)f2bf(b[1]);
  o[6] = (short)f2bf(b[2]); o[7] = (short)f2bf(b[3]);
  ((bf16x8*)xb)[i] = o;
}

// ---- prep 2: K_eff[och][kk][f] = sum_bi Q[och,kk,bi] * S[16bi+(och>>4)][och&15][f]
__global__ void keff_k(const float* __restrict__ Q, const float* __restrict__ S,
                       float* __restrict__ Keff) {
  int bid = blockIdx.x;          // = och*9 + kk
  int o = bid / 9;
  int kk = bid - o * 9;
  int f = threadIdx.x;
  int qb = o * 144 + kk * 16;
  int sb = ((o >> 4) * 16 + (o & 15)) * 256 + f;
  float acc = 0.f;
#pragma unroll
  for (int bi = 0; bi < 16; ++bi)
    acc = fmaf(Q[qb + bi], S[sb + bi * 65536], acc);
  Keff[bid * 256 + f] = acc;
}

// ---- prep 3: K2t[kk][f][ci] = sum_o P[o][ci] * Keff[o][kk][f]  (bf16, transposed)
__global__ void k2t_k(const float* __restrict__ P, const float* __restrict__ Keff,
                      unsigned short* __restrict__ K2t) {
  int kk = blockIdx.x >> 4;
  int f0 = (blockIdx.x & 15) * 16;
  int ci = threadIdx.x;
  float acc[16];
#pragma unroll
  for (int j = 0; j < 16; ++j) acc[j] = 0.f;
#pragma unroll 4
  for (int o = 0; o < 256; ++o) {
    float pv = P[o * 256 + ci];
    const float* ke = Keff + (o * 9 + kk) * 256 + f0;
#pragma unroll
    for (int j = 0; j < 16; ++j) acc[j] = fmaf(pv, ke[j], acc[j]);
  }
#pragma unroll
  for (int j = 0; j < 16; ++j)
    K2t[kk * 65536 + (f0 + j) * 256 + ci] = f2bf(acc[j]);
}

// ---- main: implicit-GEMM conv.  M=30752, N=256, K=2304 (9 taps x 256 ch)
// BM=128, BN=128, BK=64. 128 threads = 2 waves, per-wave tile 128x64
// (LDS-traffic ratio 42.7 FLOP/B vs 32 for 64x64 waves). Double-buffered
// LDS = 64KB -> 2 blocks/CU; the barrier's vmcnt(0) drain is absorbed by the
// co-resident block's compute (m97 cross-block mechanism). Grid 488 = 8x61,
// XCD chunk swizzle keeps the (n0=0, n0=128) pair sharing an A-tile on one XCD.
__global__ __launch_bounds__(128) void conv_gemm(const unsigned short* __restrict__ xb,
                                                 const unsigned short* __restrict__ K2t,
                                                 float* __restrict__ out) {
  __shared__ unsigned short ldsA[2][128 * 64];   // 2 x 16KB, XOR-swizzled
  __shared__ unsigned short ldsB[2][128 * 64];   // 2 x 16KB, XOR-swizzled

  const int tid = threadIdx.x;
  const int lane = tid & 63;
  const int w = tid >> 6;                   // wave 0..1 (n-split)

  // XCD chunk swizzle: 488 blocks = 8 XCDs x 61; pairs (2mt, 2mt+1) contiguous
  const int wgid = (blockIdx.x & 7) * 61 + (blockIdx.x >> 3);
  const int mt = wgid >> 1;                 // 0..243
  const int nt = wgid & 1;
  const int m0 = mt * 128;
  const int n0 = nt * 128;
  if (m0 >= M_TOT) return;                  // padding blocks (mt 241..243)

  // staging: thread t covers chunks t + 128j (row (t>>3)+16j, slot t&7), j=0..7.
  // T2 both-sides: source slot = (t&7) ^ (row&7); row&7 = (t>>3)&7 (16j == 0 mod 8).
  const int swslot = ((tid & 7) ^ ((tid >> 3) & 7)) * 8;
  const int rA = tid >> 3;                  // 0..15

  int gA[8];                                // A pixel base addrs (elems), swslot folded
#pragma unroll
  for (int j = 0; j < 8; ++j) {
    int m = m0 + rA + 16 * j; if (m >= M_TOT) m = M_TOT - 1;
    int b = m / 3844; int rem = m - b * 3844;
    int h = rem / 62; int wq = rem - h * 62;
    gA[j] = ((b * 64 + h) * 64 + wq) * 256 + swslot;
  }

  f32x4 zero = {0.f, 0.f, 0.f, 0.f};
  f32x4 acc[8][4];
#pragma unroll
  for (int i = 0; i < 8; ++i)
#pragma unroll
    for (int j = 0; j < 4; ++j) acc[i][j] = zero;

  const int rl = lane & 15;
  const int kg = lane >> 4;
  const int xm = (lane & 7) << 4;           // read-side XOR ((row&7)<<4), row&7==rl&7

#define STAGE(t, buf)                                                           \
  {                                                                             \
    int kk_ = (t) >> 2, cb_ = (t) & 3;                                          \
    int kh_ = kk_ / 3, kw_ = kk_ - kh_ * 3;                                     \
    int offA_ = kh_ * 16384 + kw_ * 256 + cb_ * 64;                             \
    int offB_ = kk_ * 65536 + cb_ * 64 + swslot;                                \
    _Pragma("unroll")                                                           \
    for (int j = 0; j < 8; ++j)                                                 \
      gload16(xb + gA[j] + offA_, &ldsA[buf][(tid + 128 * j) * 8]);             \
    _Pragma("unroll")                                                           \
    for (int j = 0; j < 8; ++j)                                                 \
      gload16(K2t + offB_ + (n0 + rA + 16 * j) * 256, &ldsB[buf][(tid + 128 * j) * 8]); \
  }

  STAGE(0, 0);
  __syncthreads();

  for (int t = 0; t < 36; ++t) {
    int buf = t & 1;
    if (t < 35) STAGE(t + 1, buf ^ 1);      // in flight during compute(t)

#pragma unroll
    for (int ks = 0; ks < 2; ++ks) {
      bf16x8 af[8], bfr[4];
      int cbyte = (ks * 64 + kg * 16) ^ xm;
#pragma unroll
      for (int mi = 0; mi < 8; ++mi)
        af[mi] = *(const bf16x8*)((const char*)ldsA[buf] + (mi * 16 + rl) * 128 + cbyte);
#pragma unroll
      for (int ni = 0; ni < 4; ++ni)
        bfr[ni] = *(const bf16x8*)((const char*)ldsB[buf] + (w * 64 + ni * 16 + rl) * 128 + cbyte);
#pragma unroll
      for (int mi = 0; mi < 8; ++mi)
#pragma unroll
        for (int ni = 0; ni < 4; ++ni)
          acc[mi][ni] = __builtin_amdgcn_mfma_f32_16x16x32_bf16(
              af[mi], bfr[ni], acc[mi][ni], 0, 0, 0);
    }

    __syncthreads();   // drains STAGE(t+1) (vmcnt0) + protects buf for overwrite;
                       // co-resident block's compute covers the drain
  }

  // epilogue: D row = kg*4 + r (+16*mi), col = rl (+16*ni +64*w)
#pragma unroll
  for (int mi = 0; mi < 8; ++mi) {
    int mb = m0 + mi * 16 + kg * 4;
#pragma unroll
    for (int ni = 0; ni < 4; ++ni) {
      int f = n0 + w * 64 + ni * 16 + rl;
#pragma unroll
      for (int r = 0; r < 4; ++r) {
        int m = mb + r;
        if (m < M_TOT) out[m * 256 + f] = acc[mi][ni][r];
      }
    }
  }
#undef STAGE
}

extern "C" void kernel_launch(void* const* d_in, const int* in_sizes, int n_in,
                              void* d_out, int out_size, void* d_ws, size_t ws_size,
                              hipStream_t stream) {
  const float* x = (const float*)d_in[0];   // [8,64,64,256]
  const float* P = (const float*)d_in[1];   // [256,256]
  const float* Q = (const float*)d_in[2];   // [256,3,3,16]
  const float* S = (const float*)d_in[3];   // [256,16,256]
  float* out = (float*)d_out;               // [8,62,62,256]

  char* ws = (char*)d_ws;
  unsigned short* xb   = (unsigned short*)ws;                        // 16,777,216 B
  float*          Keff = (float*)(ws + 16777216);                    //  2,359,296 B
  unsigned short* K2t  = (unsigned short*)(ws + 16777216 + 2359296); //  1,179,648 B

  cast_x<<<4096, 256, 0, stream>>>(x, xb);
  keff_k<<<2304, 256, 0, stream>>>(Q, S, Keff);
  k2t_k<<<144, 256, 0, stream>>>(P, Keff, K2t);
  conv_gemm<<<488, 128, 0, stream>>>(xb, K2t, out);
}

// Round 7
// 95.535 us; speedup vs baseline: 1.2546x; 1.2546x over previous
//
#include <hip/hip_runtime.h>
#include <hip/hip_bf16.h>

typedef __attribute__((ext_vector_type(4))) float f32x4;
typedef __attribute__((ext_vector_type(8))) short bf16x8;

#define M_TOT 30752   // 8*62*62 output pixels

__device__ __forceinline__ unsigned short f2bf(float f) {
  unsigned int u = __float_as_uint(f);
  u = u + 0x7FFF + ((u >> 16) & 1);   // round-to-nearest-even
  return (unsigned short)(u >> 16);
}

__device__ __forceinline__ void gload16(const void* g, void* l) {
  __builtin_amdgcn_global_load_lds((const __attribute__((address_space(1))) unsigned int*)g,
                                   (__attribute__((address_space(3))) unsigned int*)l,
                                   16, 0, 0);
}

// ---- prep: ONE kernel. blocks 0..4095: cast x->bf16. blocks 4096..4383:
// fused Keff+K2t: block (kk, f-slice of 8): compute Keff[o][kk][f0..f0+7]
// into LDS (Q staged in LDS), then K2t[kk][f][ci] = sum_o P[o][ci]*KeffLDS[o][f].
__global__ __launch_bounds__(256) void prep_k(const float* __restrict__ x,
                                              const float* __restrict__ P,
                                              const float* __restrict__ Q,
                                              const float* __restrict__ S,
                                              unsigned short* __restrict__ xb,
                                              unsigned short* __restrict__ K2t) {
  __shared__ float ldsQ[256 * 16];   // 16KB: Q[o][bi] at this kk
  __shared__ float ldsK[256 * 8];    //  8KB: Keff[o][j], j = f0..f0+7

  const int bid = blockIdx.x;
  const int t = threadIdx.x;

  if (bid < 4096) {                  // ---- cast_x part ----
    int i = bid * 256 + t;
    const f32x4* xp = (const f32x4*)x;
    f32x4 a = xp[2 * i];
    f32x4 b = xp[2 * i + 1];
    bf16x8 o;
    o[0] = (short)f2bf(a[0]); o[1] = (short)f2bf(a[1]);
    o[2] = (short)f2bf(a[2]); o[3] = (short)f2bf(a[3]);
    o[4] = (short)f2bf(b[0]); o[5] = (short)f2bf(b[1]);
    o[6] = (short)f2bf(b[2]); o[7] = (short)f2bf(b[3]);
    ((bf16x8*)xb)[i] = o;
    return;
  }

  const int bid2 = bid - 4096;       // 0..287
  const int kk = bid2 >> 5;          // 0..8
  const int f0 = (bid2 & 31) * 8;    // 0..248

  // stage Q[o=t][kk][0..15] -> ldsQ (16 floats, float4-aligned: 144%16==0... t*144+kk*16 mult of 16)
  {
    const f32x4* qp = (const f32x4*)(Q + t * 144 + kk * 16);
    f32x4* lq = (f32x4*)(ldsQ + t * 16);
    lq[0] = qp[0]; lq[1] = qp[1]; lq[2] = qp[2]; lq[3] = qp[3];
  }
  __syncthreads();

  // Keff[o=t][j] = sum_bi Q[o][kk][bi] * S[bi*65536 + (o>>4)*4096 + (o&15)*256 + f0 + j]
  {
    int o = t;
    const float* sp = S + (o >> 4) * 4096 + (o & 15) * 256 + f0;
    float ka[8];
#pragma unroll
    for (int j = 0; j < 8; ++j) ka[j] = 0.f;
#pragma unroll
    for (int bi = 0; bi < 16; ++bi) {
      const f32x4* s4 = (const f32x4*)(sp + bi * 65536);
      f32x4 sa = s4[0], sb = s4[1];
      float qv = ldsQ[o * 16 + bi];
      ka[0] = fmaf(qv, sa[0], ka[0]); ka[1] = fmaf(qv, sa[1], ka[1]);
      ka[2] = fmaf(qv, sa[2], ka[2]); ka[3] = fmaf(qv, sa[3], ka[3]);
      ka[4] = fmaf(qv, sb[0], ka[4]); ka[5] = fmaf(qv, sb[1], ka[5]);
      ka[6] = fmaf(qv, sb[2], ka[6]); ka[7] = fmaf(qv, sb[3], ka[7]);
    }
#pragma unroll
    for (int j = 0; j < 8; ++j) ldsK[o * 8 + j] = ka[j];
  }
  __syncthreads();

  // K2t[kk][f0+j][ci=t] = sum_o P[o][ci] * ldsK[o][j]
  {
    int ci = t;
    float acc[8];
#pragma unroll
    for (int j = 0; j < 8; ++j) acc[j] = 0.f;
#pragma unroll 4
    for (int o = 0; o < 256; ++o) {
      float pv = P[o * 256 + ci];
#pragma unroll
      for (int j = 0; j < 8; ++j) acc[j] = fmaf(pv, ldsK[o * 8 + j], acc[j]);
    }
#pragma unroll
    for (int j = 0; j < 8; ++j)
      K2t[kk * 65536 + (f0 + j) * 256 + ci] = f2bf(acc[j]);
  }
}

// ---- main: implicit-GEMM conv.  M=30752, N=256 (full), K=2304 (9 taps x 256 ch)
// BM=128, BN=256, BK=64. 512 thr (8 waves, 2m x 4n), 64x64 out per wave.
// R5 skeleton (triple-buffer, depth-2 prefetch, counted vmcnt) + T3 phase split
// (2 phases/step: ks=0, ks=1) with per-phase lgkmcnt(0)+sched_barrier fence and
// T5 setprio around each 16-MFMA cluster; stage(t+2) gloads spread 2+4.
__global__ __launch_bounds__(512) void conv_gemm(const unsigned short* __restrict__ xb,
                                                 const unsigned short* __restrict__ K2t,
                                                 float* __restrict__ out) {
  __shared__ unsigned short A0[128 * 64];   // 16KB each, XOR-swizzled
  __shared__ unsigned short A1[128 * 64];
  __shared__ unsigned short A2[128 * 64];
  __shared__ unsigned short B0[256 * 64];   // 32KB each, XOR-swizzled
  __shared__ unsigned short B1[256 * 64];
  __shared__ unsigned short B2[256 * 64];

  const int tid = threadIdx.x;
  const int lane = tid & 63;
  const int wm = (tid >> 6) >> 2;   // 0..1
  const int wn = (tid >> 6) & 3;    // 0..3
  const int m0 = blockIdx.x * 128;

  // staging: thread t covers LDS chunk (row t>>3, slot t&7) [+512-chunk repeats].
  // T2 both-sides: source slot = (t&7) ^ (row&7); reader XORs identically.
  const int swslot = ((tid & 7) ^ ((tid >> 3) & 7)) * 8;
  const int rA = tid >> 3;          // 0..63

  int gA0, gA1;
  {
    int m = m0 + rA; if (m >= M_TOT) m = M_TOT - 1;
    int b = m / 3844; int rem = m - b * 3844;
    int h = rem / 62; int w = rem - h * 62;
    gA0 = ((b * 64 + h) * 64 + w) * 256 + swslot;
    m = m0 + rA + 64; if (m >= M_TOT) m = M_TOT - 1;
    b = m / 3844; rem = m - b * 3844;
    h = rem / 62; w = rem - h * 62;
    gA1 = ((b * 64 + h) * 64 + w) * 256 + swslot;
  }

  f32x4 zero = {0.f, 0.f, 0.f, 0.f};
  f32x4 acc[4][4];
#pragma unroll
  for (int i = 0; i < 4; ++i)
#pragma unroll
    for (int j = 0; j < 4; ++j) acc[i][j] = zero;

  const int rl = lane & 15;
  const int kg = lane >> 4;
  const int xm = (lane & 7) << 4;   // read-side XOR: (row&7)<<4, row&7 == lane&7

#define STAGE_A(t, bufA)                                                       \
  {                                                                            \
    int kk_ = (t) >> 2, cb_ = (t) & 3;                                         \
    int kh_ = kk_ / 3, kw_ = kk_ - kh_ * 3;                                    \
    int offA_ = kh_ * 16384 + kw_ * 256 + cb_ * 64;                            \
    gload16(xb + gA0 + offA_, &bufA[tid * 8]);                                 \
    gload16(xb + gA1 + offA_, &bufA[(tid + 512) * 8]);                         \
  }

#define STAGE_B(t, bufB)                                                       \
  {                                                                            \
    int kk_ = (t) >> 2, cb_ = (t) & 3;                                         \
    int offB_ = kk_ * 65536 + cb_ * 64 + swslot;                               \
    _Pragma("unroll")                                                          \
    for (int q = 0; q < 4; ++q)                                                \
      gload16(K2t + offB_ + (rA + 64 * q) * 256, &bufB[(tid + 512 * q) * 8]);  \
  }

  // one phase: 8 ds_read (ks slice) -> spread gloads -> lgkm fence -> 16 MFMA
#define PHASE(ks, bufA, bufB, STAGE_STMT)                                      \
  {                                                                            \
    bf16x8 af[4], bfr[4];                                                      \
    int cbyte = ((ks) * 64 + kg * 16) ^ xm;                                    \
    _Pragma("unroll")                                                          \
    for (int mi = 0; mi < 4; ++mi)                                             \
      af[mi] = *(const bf16x8*)((const char*)bufA + (wm * 64 + mi * 16 + rl) * 128 + cbyte); \
    _Pragma("unroll")                                                          \
    for (int ni = 0; ni < 4; ++ni)                                             \
      bfr[ni] = *(const bf16x8*)((const char*)bufB + (wn * 64 + ni * 16 + rl) * 128 + cbyte); \
    STAGE_STMT;                                                                \
    asm volatile("s_waitcnt lgkmcnt(0)" ::: "memory");                         \
    __builtin_amdgcn_sched_barrier(0);                                         \
    __builtin_amdgcn_s_setprio(1);                                             \
    _Pragma("unroll")                                                          \
    for (int mi = 0; mi < 4; ++mi)                                             \
      _Pragma("unroll")                                                        \
      for (int ni = 0; ni < 4; ++ni)                                           \
        acc[mi][ni] = __builtin_amdgcn_mfma_f32_16x16x32_bf16(                 \
            af[mi], bfr[ni], acc[mi][ni], 0, 0, 0);                            \
    __builtin_amdgcn_s_setprio(0);                                             \
  }

  // step: preamble counted-vmcnt barrier, then 2 phases with mid raw barrier
#define STEP(t, cA, cB, nA, nB)                                                \
  {                                                                            \
    if ((t) == 35) asm volatile("s_waitcnt vmcnt(0)" ::: "memory");            \
    else           asm volatile("s_waitcnt vmcnt(6)" ::: "memory");            \
    __builtin_amdgcn_sched_barrier(0);                                         \
    __builtin_amdgcn_s_barrier();                                              \
    __builtin_amdgcn_sched_barrier(0);                                         \
    PHASE(0, cA, cB, { if ((t) + 2 < 36) STAGE_A((t) + 2, nA); })              \
    __builtin_amdgcn_sched_barrier(0);                                         \
    __builtin_amdgcn_s_barrier();                                              \
    __builtin_amdgcn_sched_barrier(0);                                         \
    PHASE(1, cA, cB, { if ((t) + 2 < 36) STAGE_B((t) + 2, nB); })              \
  }

  STAGE_A(0, A0); STAGE_B(0, B0);
  STAGE_A(1, A1); STAGE_B(1, B1);

  for (int tt = 0; tt < 12; ++tt) {
    int t0 = tt * 3;
    STEP(t0,     A0, B0, A2, B2);
    STEP(t0 + 1, A1, B1, A0, B0);
    STEP(t0 + 2, A2, B2, A1, B1);
  }

  // epilogue: D row = kg*4 + r (+16*mi +64*wm), col = rl (+16*ni +64*wn)
#pragma unroll
  for (int mi = 0; mi < 4; ++mi) {
    int mb = m0 + wm * 64 + mi * 16 + kg * 4;
#pragma unroll
    for (int ni = 0; ni < 4; ++ni) {
      int f = wn * 64 + ni * 16 + rl;
#pragma unroll
      for (int r = 0; r < 4; ++r) {
        int m = mb + r;
        if (m < M_TOT) out[m * 256 + f] = acc[mi][ni][r];
      }
    }
  }
#undef STAGE_A
#undef STAGE_B
#undef PHASE
#undef STEP
}

extern "C" void kernel_launch(void* const* d_in, const int* in_sizes, int n_in,
                              void* d_out, int out_size, void* d_ws, size_t ws_size,
                              hipStream_t stream) {
  const float* x = (const float*)d_in[0];   // [8,64,64,256]
  const float* P = (const float*)d_in[1];   // [256,256]
  const float* Q = (const float*)d_in[2];   // [256,3,3,16]
  const float* S = (const float*)d_in[3];   // [256,16,256]
  float* out = (float*)d_out;               // [8,62,62,256]

  char* ws = (char*)d_ws;
  unsigned short* xb  = (unsigned short*)ws;               // 16,777,216 B
  unsigned short* K2t = (unsigned short*)(ws + 16777216);  //  1,179,648 B

  prep_k<<<4096 + 288, 256, 0, stream>>>(x, P, Q, S, xb, K2t);
  conv_gemm<<<241, 512, 0, stream>>>(xb, K2t, out);
}

// Round 8
// 80.267 us; speedup vs baseline: 1.4932x; 1.1902x over previous
//
#include <hip/hip_runtime.h>
#include <hip/hip_bf16.h>

typedef __attribute__((ext_vector_type(4))) float f32x4;
typedef __attribute__((ext_vector_type(8))) short bf16x8;

#define M_TOT 30752   // 8*62*62 output pixels

__device__ __forceinline__ unsigned short f2bf(float f) {
  unsigned int u = __float_as_uint(f);
  u = u + 0x7FFF + ((u >> 16) & 1);   // round-to-nearest-even
  return (unsigned short)(u >> 16);
}

__device__ __forceinline__ void gload16(const void* g, void* l) {
  __builtin_amdgcn_global_load_lds((const __attribute__((address_space(1))) unsigned int*)g,
                                   (__attribute__((address_space(3))) unsigned int*)l,
                                   16, 0, 0);
}

// ---- prep1: blocks 0..4095 cast x->bf16; blocks 4096..6399 keff.
// keff block = (o, kk) [2304 blocks, ~9/CU], thread = f:
//   Keff[o][kk][f] = sum_bi Q[o,kk,bi] * S[bi*65536 + (o>>4)*4096 + (o&15)*256 + f]
// S reads contiguous across f (coalesced); Q uniform (scalar loads); 16
// independent loads/thread -> latency hidden by occupancy.
__global__ __launch_bounds__(256) void prep1(const float* __restrict__ x,
                                             const float* __restrict__ Q,
                                             const float* __restrict__ S,
                                             unsigned short* __restrict__ xb,
                                             float* __restrict__ Keff) {
  const int bid = blockIdx.x;
  const int t = threadIdx.x;

  if (bid < 4096) {                  // ---- cast x -> bf16 ----
    int i = bid * 256 + t;
    const f32x4* xp = (const f32x4*)x;
    f32x4 a = xp[2 * i];
    f32x4 b = xp[2 * i + 1];
    bf16x8 o;
    o[0] = (short)f2bf(a[0]); o[1] = (short)f2bf(a[1]);
    o[2] = (short)f2bf(a[2]); o[3] = (short)f2bf(a[3]);
    o[4] = (short)f2bf(b[0]); o[5] = (short)f2bf(b[1]);
    o[6] = (short)f2bf(b[2]); o[7] = (short)f2bf(b[3]);
    ((bf16x8*)xb)[i] = o;
    return;
  }

  const int bid2 = bid - 4096;       // 0..2303  = o*9 + kk
  const int o = bid2 / 9;
  const int kk = bid2 - o * 9;
  const int f = t;
  const int qb = o * 144 + kk * 16;                     // uniform -> s_load
  const int sb = (o >> 4) * 4096 + (o & 15) * 256 + f;  // coalesced across f
  float acc = 0.f;
#pragma unroll
  for (int bi = 0; bi < 16; ++bi)
    acc = fmaf(Q[qb + bi], S[sb + bi * 65536], acc);
  Keff[bid2 * 256 + f] = acc;
}

// ---- prep2: K2t[kk][f][ci] = sum_o P[o][ci] * Keff[o][kk][f]  (bf16, transposed)
// 576 blocks (9 kk x 64 f-slices of 4) ~ 2.25/CU; unroll-8 o-loop keeps 8
// P-rows (coalesced v-loads) + 8 Keff quads (uniform s_load_dwordx4) in flight.
__global__ __launch_bounds__(256) void k2t_k(const float* __restrict__ P,
                                             const float* __restrict__ Keff,
                                             unsigned short* __restrict__ K2t) {
  const int kk = blockIdx.x >> 6;        // 0..8
  const int f0 = (blockIdx.x & 63) * 4;  // 0..252
  const int ci = threadIdx.x;
  float acc[4] = {0.f, 0.f, 0.f, 0.f};
#pragma unroll 8
  for (int o = 0; o < 256; ++o) {
    float pv = P[o * 256 + ci];                        // coalesced
    const float* ke = Keff + (o * 9 + kk) * 256 + f0;  // uniform -> s_load_dwordx4
    acc[0] = fmaf(pv, ke[0], acc[0]);
    acc[1] = fmaf(pv, ke[1], acc[1]);
    acc[2] = fmaf(pv, ke[2], acc[2]);
    acc[3] = fmaf(pv, ke[3], acc[3]);
  }
#pragma unroll
  for (int j = 0; j < 4; ++j)
    K2t[kk * 65536 + (f0 + j) * 256 + ci] = f2bf(acc[j]);
}

// ---- main: implicit-GEMM conv.  M=30752, N=256 (full), K=2304 (9 taps x 256 ch)
// BM=128, BN=256, BK=64. 512 thr (8 waves, 2m x 4n), 64x64 out per wave.
// Triple-buffer, depth-2 prefetch, counted vmcnt + T3 phase split (2 phases/step)
// with per-phase lgkmcnt(0)+sched_barrier fence and T5 setprio around each
// 16-MFMA cluster; stage(t+2) gloads spread 2+4.  [R7 structure, unchanged]
__global__ __launch_bounds__(512) void conv_gemm(const unsigned short* __restrict__ xb,
                                                 const unsigned short* __restrict__ K2t,
                                                 float* __restrict__ out) {
  __shared__ unsigned short A0[128 * 64];   // 16KB each, XOR-swizzled
  __shared__ unsigned short A1[128 * 64];
  __shared__ unsigned short A2[128 * 64];
  __shared__ unsigned short B0[256 * 64];   // 32KB each, XOR-swizzled
  __shared__ unsigned short B1[256 * 64];
  __shared__ unsigned short B2[256 * 64];

  const int tid = threadIdx.x;
  const int lane = tid & 63;
  const int wm = (tid >> 6) >> 2;   // 0..1
  const int wn = (tid >> 6) & 3;    // 0..3
  const int m0 = blockIdx.x * 128;

  // staging: thread t covers LDS chunk (row t>>3, slot t&7) [+512-chunk repeats].
  // T2 both-sides: source slot = (t&7) ^ (row&7); reader XORs identically.
  const int swslot = ((tid & 7) ^ ((tid >> 3) & 7)) * 8;
  const int rA = tid >> 3;          // 0..63

  int gA0, gA1;
  {
    int m = m0 + rA; if (m >= M_TOT) m = M_TOT - 1;
    int b = m / 3844; int rem = m - b * 3844;
    int h = rem / 62; int w = rem - h * 62;
    gA0 = ((b * 64 + h) * 64 + w) * 256 + swslot;
    m = m0 + rA + 64; if (m >= M_TOT) m = M_TOT - 1;
    b = m / 3844; rem = m - b * 3844;
    h = rem / 62; w = rem - h * 62;
    gA1 = ((b * 64 + h) * 64 + w) * 256 + swslot;
  }

  f32x4 zero = {0.f, 0.f, 0.f, 0.f};
  f32x4 acc[4][4];
#pragma unroll
  for (int i = 0; i < 4; ++i)
#pragma unroll
    for (int j = 0; j < 4; ++j) acc[i][j] = zero;

  const int rl = lane & 15;
  const int kg = lane >> 4;
  const int xm = (lane & 7) << 4;   // read-side XOR: (row&7)<<4, row&7 == lane&7

#define STAGE_A(t, bufA)                                                       \
  {                                                                            \
    int kk_ = (t) >> 2, cb_ = (t) & 3;                                         \
    int kh_ = kk_ / 3, kw_ = kk_ - kh_ * 3;                                    \
    int offA_ = kh_ * 16384 + kw_ * 256 + cb_ * 64;                            \
    gload16(xb + gA0 + offA_, &bufA[tid * 8]);                                 \
    gload16(xb + gA1 + offA_, &bufA[(tid + 512) * 8]);                         \
  }

#define STAGE_B(t, bufB)                                                       \
  {                                                                            \
    int kk_ = (t) >> 2, cb_ = (t) & 3;                                         \
    int offB_ = kk_ * 65536 + cb_ * 64 + swslot;                               \
    _Pragma("unroll")                                                          \
    for (int q = 0; q < 4; ++q)                                                \
      gload16(K2t + offB_ + (rA + 64 * q) * 256, &bufB[(tid + 512 * q) * 8]);  \
  }

  // one phase: 8 ds_read (ks slice) -> spread gloads -> lgkm fence -> 16 MFMA
#define PHASE(ks, bufA, bufB, STAGE_STMT)                                      \
  {                                                                            \
    bf16x8 af[4], bfr[4];                                                      \
    int cbyte = ((ks) * 64 + kg * 16) ^ xm;                                    \
    _Pragma("unroll")                                                          \
    for (int mi = 0; mi < 4; ++mi)                                             \
      af[mi] = *(const bf16x8*)((const char*)bufA + (wm * 64 + mi * 16 + rl) * 128 + cbyte); \
    _Pragma("unroll")                                                          \
    for (int ni = 0; ni < 4; ++ni)                                             \
      bfr[ni] = *(const bf16x8*)((const char*)bufB + (wn * 64 + ni * 16 + rl) * 128 + cbyte); \
    STAGE_STMT;                                                                \
    asm volatile("s_waitcnt lgkmcnt(0)" ::: "memory");                         \
    __builtin_amdgcn_sched_barrier(0);                                         \
    __builtin_amdgcn_s_setprio(1);                                             \
    _Pragma("unroll")                                                          \
    for (int mi = 0; mi < 4; ++mi)                                             \
      _Pragma("unroll")                                                        \
      for (int ni = 0; ni < 4; ++ni)                                           \
        acc[mi][ni] = __builtin_amdgcn_mfma_f32_16x16x32_bf16(                 \
            af[mi], bfr[ni], acc[mi][ni], 0, 0, 0);                            \
    __builtin_amdgcn_s_setprio(0);                                             \
  }

  // step: preamble counted-vmcnt barrier, then 2 phases with mid raw barrier
#define STEP(t, cA, cB, nA, nB)                                                \
  {                                                                            \
    if ((t) == 35) asm volatile("s_waitcnt vmcnt(0)" ::: "memory");            \
    else           asm volatile("s_waitcnt vmcnt(6)" ::: "memory");            \
    __builtin_amdgcn_sched_barrier(0);                                         \
    __builtin_amdgcn_s_barrier();                                              \
    __builtin_amdgcn_sched_barrier(0);                                         \
    PHASE(0, cA, cB, { if ((t) + 2 < 36) STAGE_A((t) + 2, nA); })              \
    __builtin_amdgcn_sched_barrier(0);                                         \
    __builtin_amdgcn_s_barrier();                                              \
    __builtin_amdgcn_sched_barrier(0);                                         \
    PHASE(1, cA, cB, { if ((t) + 2 < 36) STAGE_B((t) + 2, nB); })              \
  }

  STAGE_A(0, A0); STAGE_B(0, B0);
  STAGE_A(1, A1); STAGE_B(1, B1);

  for (int tt = 0; tt < 12; ++tt) {
    int t0 = tt * 3;
    STEP(t0,     A0, B0, A2, B2);
    STEP(t0 + 1, A1, B1, A0, B0);
    STEP(t0 + 2, A2, B2, A1, B1);
  }

  // epilogue: D row = kg*4 + r (+16*mi +64*wm), col = rl (+16*ni +64*wn)
#pragma unroll
  for (int mi = 0; mi < 4; ++mi) {
    int mb = m0 + wm * 64 + mi * 16 + kg * 4;
#pragma unroll
    for (int ni = 0; ni < 4; ++ni) {
      int f = wn * 64 + ni * 16 + rl;
#pragma unroll
      for (int r = 0; r < 4; ++r) {
        int m = mb + r;
        if (m < M_TOT) out[m * 256 + f] = acc[mi][ni][r];
      }
    }
  }
#undef STAGE_A
#undef STAGE_B
#undef PHASE
#undef STEP
}

extern "C" void kernel_launch(void* const* d_in, const int* in_sizes, int n_in,
                              void* d_out, int out_size, void* d_ws, size_t ws_size,
                              hipStream_t stream) {
  const float* x = (const float*)d_in[0];   // [8,64,64,256]
  const float* P = (const float*)d_in[1];   // [256,256]
  const float* Q = (const float*)d_in[2];   // [256,3,3,16]
  const float* S = (const float*)d_in[3];   // [256,16,256]
  float* out = (float*)d_out;               // [8,62,62,256]

  char* ws = (char*)d_ws;
  unsigned short* xb   = (unsigned short*)ws;                        // 16,777,216 B
  unsigned short* K2t  = (unsigned short*)(ws + 16777216);           //  1,179,648 B
  float*          Keff = (float*)(ws + 16777216 + 1179648);          //  2,359,296 B

  prep1<<<4096 + 2304, 256, 0, stream>>>(x, Q, S, xb, Keff);
  k2t_k<<<576, 256, 0, stream>>>(P, Keff, K2t);
  conv_gemm<<<241, 512, 0, stream>>>(xb, K2t, out);
}

// Round 9
// 77.757 us; speedup vs baseline: 1.5414x; 1.0323x over previous
//
#include <hip/hip_runtime.h>
#include <hip/hip_bf16.h>

typedef __attribute__((ext_vector_type(4))) float f32x4;
typedef __attribute__((ext_vector_type(8))) short bf16x8;

#define M_TOT 30752   // 8*62*62 output pixels

__device__ __forceinline__ unsigned short f2bf(float f) {
  unsigned int u = __float_as_uint(f);
  u = u + 0x7FFF + ((u >> 16) & 1);   // round-to-nearest-even
  return (unsigned short)(u >> 16);
}

__device__ __forceinline__ void gload16(const void* g, void* l) {
  __builtin_amdgcn_global_load_lds((const __attribute__((address_space(1))) unsigned int*)g,
                                   (__attribute__((address_space(3))) unsigned int*)l,
                                   16, 0, 0);
}

// ---- prep1: blocks 0..4095 cast x->bf16; blocks 4096..4351: keff per o.
// Block = o (256 blocks), thread = f. S slice read ONCE (16 coalesced rows),
// then all 9 taps computed from registers: S traffic 4MB total (was 37MB).
__global__ __launch_bounds__(256) void prep1(const float* __restrict__ x,
                                             const float* __restrict__ Q,
                                             const float* __restrict__ S,
                                             unsigned short* __restrict__ xb,
                                             float* __restrict__ Keff) {
  const int bid = blockIdx.x;
  const int t = threadIdx.x;

  if (bid < 4096) {                  // ---- cast x -> bf16 ----
    int i = bid * 256 + t;
    const f32x4* xp = (const f32x4*)x;
    f32x4 a = xp[2 * i];
    f32x4 b = xp[2 * i + 1];
    bf16x8 o;
    o[0] = (short)f2bf(a[0]); o[1] = (short)f2bf(a[1]);
    o[2] = (short)f2bf(a[2]); o[3] = (short)f2bf(a[3]);
    o[4] = (short)f2bf(b[0]); o[5] = (short)f2bf(b[1]);
    o[6] = (short)f2bf(b[2]); o[7] = (short)f2bf(b[3]);
    ((bf16x8*)xb)[i] = o;
    return;
  }

  const int o = bid - 4096;          // 0..255
  float s[16];
  const float* sp = S + (o >> 4) * 4096 + (o & 15) * 256 + t;   // coalesced across f
#pragma unroll
  for (int bi = 0; bi < 16; ++bi) s[bi] = sp[bi * 65536];
  const float* qp = Q + o * 144;                                 // uniform -> s_load
#pragma unroll
  for (int kk = 0; kk < 9; ++kk) {
    float a = 0.f;
#pragma unroll
    for (int bi = 0; bi < 16; ++bi) a = fmaf(qp[kk * 16 + bi], s[bi], a);
    Keff[(o * 9 + kk) * 256 + t] = a;
  }
}

// ---- prep2: K2t[kk][f][ci] = sum_o P[o][ci] * Keff[o][kk][f]  (bf16, transposed)
__global__ __launch_bounds__(256) void k2t_k(const float* __restrict__ P,
                                             const float* __restrict__ Keff,
                                             unsigned short* __restrict__ K2t) {
  const int kk = blockIdx.x >> 6;        // 0..8
  const int f0 = (blockIdx.x & 63) * 4;  // 0..252
  const int ci = threadIdx.x;
  float acc[4] = {0.f, 0.f, 0.f, 0.f};
#pragma unroll 8
  for (int o = 0; o < 256; ++o) {
    float pv = P[o * 256 + ci];                        // coalesced
    const float* ke = Keff + (o * 9 + kk) * 256 + f0;  // uniform -> s_load_dwordx4
    acc[0] = fmaf(pv, ke[0], acc[0]);
    acc[1] = fmaf(pv, ke[1], acc[1]);
    acc[2] = fmaf(pv, ke[2], acc[2]);
    acc[3] = fmaf(pv, ke[3], acc[3]);
  }
#pragma unroll
  for (int j = 0; j < 4; ++j)
    K2t[kk * 65536 + (f0 + j) * 256 + ci] = f2bf(acc[j]);
}

// ---- main: implicit-GEMM conv.  M=30752, N=256, K=2304.
// BM=128, BN=256, BK=64 per step; 8 waves = (sk, wn) in 2x4: wave computes a
// 128x64 output tile over its K-HALF (32) -> LDS reads 96 instr/step (was 128),
// 32-MFMA cluster/wave, 1 barrier/step. 64B LDS rows (BK=32) make the slot
// pattern (4*rl+kg)%8 bank-uniform -> NO swizzle anywhere. Triple-buffer
// (144KB), depth-2 prefetch, counted vmcnt(6). Epilogue: sk=1 acc -> LDS,
// sk=0 adds + stores (2 rounds x 64KB).
__global__ __launch_bounds__(512, 2) void conv_gemm(const unsigned short* __restrict__ xb,
                                                    const unsigned short* __restrict__ K2t,
                                                    float* __restrict__ out) {
  __shared__ __attribute__((aligned(16))) char smem[147456];   // 144KB
  unsigned short* const A0 = (unsigned short*)(smem);            // 16KB: [2 sk][128 m][64B]
  unsigned short* const B0 = (unsigned short*)(smem + 16384);    // 32KB: [2 sk][256 f][64B]
  unsigned short* const A1 = (unsigned short*)(smem + 49152);
  unsigned short* const B1 = (unsigned short*)(smem + 65536);
  unsigned short* const A2 = (unsigned short*)(smem + 98304);
  unsigned short* const B2 = (unsigned short*)(smem + 114688);
  float* const red = (float*)smem;                               // 64KB, after main loop

  const int tid = threadIdx.x;
  const int lane = tid & 63;
  const int sk = tid >> 8;          // k-half 0..1
  const int wn = (tid >> 6) & 3;    // n-quarter 0..3
  const int m0 = blockIdx.x * 128;

  const int rl = lane & 15;
  const int kg = lane >> 4;

  // staging: thread t owns A chunks {t, t+512} (row t>>2, slot t&3, sk 0/1)
  // and B chunks {t, t+512, t+1024, t+1536} (f rows t>>2, t>>2+128; sk 0/1).
  int gAa;                          // A pixel base addr (elements), slot folded
  {
    int m = m0 + (tid >> 2); if (m >= M_TOT) m = M_TOT - 1;
    int b = m / 3844; int rem = m - b * 3844;
    int h = rem / 62; int w = rem - h * 62;
    gAa = ((b * 64 + h) * 64 + w) * 256 + (tid & 3) * 8;
  }
  const int fB0 = (tid >> 2) * 256 + (tid & 3) * 8;          // B row base (elements)
  const int fB1 = ((tid >> 2) + 128) * 256 + (tid & 3) * 8;

  f32x4 zero = {0.f, 0.f, 0.f, 0.f};
  f32x4 acc[8][4];
#pragma unroll
  for (int i = 0; i < 8; ++i)
#pragma unroll
    for (int j = 0; j < 4; ++j) acc[i][j] = zero;

  const int aoff = sk * 8192 + rl * 64 + kg * 16;                   // bytes
  const int boff = sk * 16384 + (wn * 64 + rl) * 64 + kg * 16;      // bytes

#define STAGE(t, bufA, bufB)                                                   \
  {                                                                            \
    int kk_ = (t) >> 2, cb_ = (t) & 3;                                         \
    int kh_ = kk_ / 3, kw_ = kk_ - kh_ * 3;                                    \
    int offA_ = kh_ * 16384 + kw_ * 256 + cb_ * 64;                            \
    int offB_ = kk_ * 65536 + cb_ * 64;                                        \
    gload16(xb + gAa + offA_,       &bufA[tid * 8]);                           \
    gload16(xb + gAa + offA_ + 32,  &bufA[(tid + 512) * 8]);                   \
    gload16(K2t + offB_ + fB0,      &bufB[tid * 8]);                           \
    gload16(K2t + offB_ + fB1,      &bufB[(tid + 512) * 8]);                   \
    gload16(K2t + offB_ + fB0 + 32, &bufB[(tid + 1024) * 8]);                  \
    gload16(K2t + offB_ + fB1 + 32, &bufB[(tid + 1536) * 8]);                  \
  }

#define STEP(t, cA, cB, nA, nB)                                                \
  {                                                                            \
    if ((t) == 35) asm volatile("s_waitcnt vmcnt(0)" ::: "memory");            \
    else           asm volatile("s_waitcnt vmcnt(6)" ::: "memory");            \
    __builtin_amdgcn_sched_barrier(0);                                         \
    __builtin_amdgcn_s_barrier();                                              \
    __builtin_amdgcn_sched_barrier(0);                                         \
    bf16x8 af[8], bfr[4];                                                      \
    _Pragma("unroll")                                                          \
    for (int mi = 0; mi < 8; ++mi)                                             \
      af[mi] = *(const bf16x8*)((const char*)(cA) + aoff + mi * 1024);         \
    _Pragma("unroll")                                                          \
    for (int ni = 0; ni < 4; ++ni)                                             \
      bfr[ni] = *(const bf16x8*)((const char*)(cB) + boff + ni * 1024);        \
    if ((t) < 34) { STAGE((t) + 2, nA, nB); }                                  \
    asm volatile("s_waitcnt lgkmcnt(0)" ::: "memory");                         \
    __builtin_amdgcn_sched_barrier(0);                                         \
    __builtin_amdgcn_s_setprio(1);                                             \
    _Pragma("unroll")                                                          \
    for (int mi = 0; mi < 8; ++mi)                                             \
      _Pragma("unroll")                                                        \
      for (int ni = 0; ni < 4; ++ni)                                           \
        acc[mi][ni] = __builtin_amdgcn_mfma_f32_16x16x32_bf16(                 \
            af[mi], bfr[ni], acc[mi][ni], 0, 0, 0);                            \
    __builtin_amdgcn_s_setprio(0);                                             \
  }

  STAGE(0, A0, B0);
  STAGE(1, A1, B1);

  for (int tt = 0; tt < 12; ++tt) {
    int t0 = tt * 3;
    STEP(t0,     A0, B0, A2, B2);
    STEP(t0 + 1, A1, B1, A0, B0);
    STEP(t0 + 2, A2, B2, A1, B1);
  }

  __syncthreads();   // main loop done; smem reused as reduction buffer

  // epilogue: sk=1 waves stage acc in LDS; sk=0 adds + stores.
  // D row = kg*4 + r (+16*mi), col = rl (+16*ni +64*wn).
#pragma unroll
  for (int round = 0; round < 2; ++round) {
    if (sk == 1) {
#pragma unroll
      for (int mc = 0; mc < 4; ++mc)
#pragma unroll
        for (int ni = 0; ni < 4; ++ni)
          *(f32x4*)((char*)red + (((wn * 4 + mc) * 4 + ni) * 64 + lane) * 16) =
              acc[round * 4 + mc][ni];
    }
    __syncthreads();
    if (sk == 0) {
#pragma unroll
      for (int mc = 0; mc < 4; ++mc) {
        int mi = round * 4 + mc;
        int mb = m0 + mi * 16 + kg * 4;
#pragma unroll
        for (int ni = 0; ni < 4; ++ni) {
          f32x4 o = *(f32x4*)((char*)red + (((wn * 4 + mc) * 4 + ni) * 64 + lane) * 16);
          o += acc[mi][ni];
          int f = wn * 64 + ni * 16 + rl;
#pragma unroll
          for (int r = 0; r < 4; ++r) {
            int m = mb + r;
            if (m < M_TOT) out[m * 256 + f] = o[r];
          }
        }
      }
    }
    __syncthreads();
  }
#undef STAGE
#undef STEP
}

extern "C" void kernel_launch(void* const* d_in, const int* in_sizes, int n_in,
                              void* d_out, int out_size, void* d_ws, size_t ws_size,
                              hipStream_t stream) {
  const float* x = (const float*)d_in[0];   // [8,64,64,256]
  const float* P = (const float*)d_in[1];   // [256,256]
  const float* Q = (const float*)d_in[2];   // [256,3,3,16]
  const float* S = (const float*)d_in[3];   // [256,16,256]
  float* out = (float*)d_out;               // [8,62,62,256]

  char* ws = (char*)d_ws;
  unsigned short* xb   = (unsigned short*)ws;                        // 16,777,216 B
  unsigned short* K2t  = (unsigned short*)(ws + 16777216);           //  1,179,648 B
  float*          Keff = (float*)(ws + 16777216 + 1179648);          //  2,359,296 B

  prep1<<<4096 + 256, 256, 0, stream>>>(x, Q, S, xb, Keff);
  k2t_k<<<576, 256, 0, stream>>>(P, Keff, K2t);
  conv_gemm<<<241, 512, 0, stream>>>(xb, K2t, out);
}

// Round 10
// 76.266 us; speedup vs baseline: 1.5716x; 1.0195x over previous
//
#include <hip/hip_runtime.h>
#include <hip/hip_bf16.h>

typedef __attribute__((ext_vector_type(4))) float f32x4;
typedef __attribute__((ext_vector_type(8))) short bf16x8;

#define M_TOT 30752   // 8*62*62 output pixels

__device__ __forceinline__ unsigned short f2bf(float f) {
  unsigned int u = __float_as_uint(f);
  u = u + 0x7FFF + ((u >> 16) & 1);   // round-to-nearest-even
  return (unsigned short)(u >> 16);
}

__device__ __forceinline__ void gload16(const void* g, void* l) {
  __builtin_amdgcn_global_load_lds((const __attribute__((address_space(1))) unsigned int*)g,
                                   (__attribute__((address_space(3))) unsigned int*)l,
                                   16, 0, 0);
}

// ---- prep1: blocks 0..4095 cast x->bf16; blocks 4096..4351: keff per o.
__global__ __launch_bounds__(256) void prep1(const float* __restrict__ x,
                                             const float* __restrict__ Q,
                                             const float* __restrict__ S,
                                             unsigned short* __restrict__ xb,
                                             float* __restrict__ Keff) {
  const int bid = blockIdx.x;
  const int t = threadIdx.x;

  if (bid < 4096) {                  // ---- cast x -> bf16 ----
    int i = bid * 256 + t;
    const f32x4* xp = (const f32x4*)x;
    f32x4 a = xp[2 * i];
    f32x4 b = xp[2 * i + 1];
    bf16x8 o;
    o[0] = (short)f2bf(a[0]); o[1] = (short)f2bf(a[1]);
    o[2] = (short)f2bf(a[2]); o[3] = (short)f2bf(a[3]);
    o[4] = (short)f2bf(b[0]); o[5] = (short)f2bf(b[1]);
    o[6] = (short)f2bf(b[2]); o[7] = (short)f2bf(b[3]);
    ((bf16x8*)xb)[i] = o;
    return;
  }

  const int o = bid - 4096;          // 0..255
  float s[16];
  const float* sp = S + (o >> 4) * 4096 + (o & 15) * 256 + t;   // coalesced across f
#pragma unroll
  for (int bi = 0; bi < 16; ++bi) s[bi] = sp[bi * 65536];
  const float* qp = Q + o * 144;                                 // uniform -> s_load
#pragma unroll
  for (int kk = 0; kk < 9; ++kk) {
    float a = 0.f;
#pragma unroll
    for (int bi = 0; bi < 16; ++bi) a = fmaf(qp[kk * 16 + bi], s[bi], a);
    Keff[(o * 9 + kk) * 256 + t] = a;
  }
}

// ---- prep2: K2t[kk][f][ci] = sum_o P[o][ci] * Keff[o][kk][f]  (bf16, transposed)
__global__ __launch_bounds__(256) void k2t_k(const float* __restrict__ P,
                                             const float* __restrict__ Keff,
                                             unsigned short* __restrict__ K2t) {
  const int kk = blockIdx.x >> 6;        // 0..8
  const int f0 = (blockIdx.x & 63) * 4;  // 0..252
  const int ci = threadIdx.x;
  float acc[4] = {0.f, 0.f, 0.f, 0.f};
#pragma unroll 8
  for (int o = 0; o < 256; ++o) {
    float pv = P[o * 256 + ci];                        // coalesced
    const float* ke = Keff + (o * 9 + kk) * 256 + f0;  // uniform -> s_load_dwordx4
    acc[0] = fmaf(pv, ke[0], acc[0]);
    acc[1] = fmaf(pv, ke[1], acc[1]);
    acc[2] = fmaf(pv, ke[2], acc[2]);
    acc[3] = fmaf(pv, ke[3], acc[3]);
  }
#pragma unroll
  for (int j = 0; j < 4; ++j)
    K2t[kk * 65536 + (f0 + j) * 256 + ci] = f2bf(acc[j]);
}

// ---- main: implicit-GEMM conv.  M=30752, N=256, K=2304.
// BM=128, BN=256, BK=64/step; waves (sk, wn) in 2x4, each a 128x64 tile over
// its K-half. 64B LDS rows: conflict-free via slot' = slot ^ ((row>>1)&3)
// on BOTH sides (pre-swizzled global source; XOR'd read) -- verified: every
// 8-lane group hits 8 distinct 16B columns. No manual lgkmcnt drain: compiler
// emits fine-grained counted lgkmcnt so early MFMAs overlap late ds_reads.
// Triple-buffer, depth-2 prefetch, counted vmcnt(6); setprio on MFMA cluster.
__global__ __launch_bounds__(512, 2) void conv_gemm(const unsigned short* __restrict__ xb,
                                                    const unsigned short* __restrict__ K2t,
                                                    float* __restrict__ out) {
  __shared__ __attribute__((aligned(16))) char smem[147456];   // 144KB
  unsigned short* const A0 = (unsigned short*)(smem);            // 16KB: [2 sk][128 m][64B]
  unsigned short* const B0 = (unsigned short*)(smem + 16384);    // 32KB: [2 sk][256 f][64B]
  unsigned short* const A1 = (unsigned short*)(smem + 49152);
  unsigned short* const B1 = (unsigned short*)(smem + 65536);
  unsigned short* const A2 = (unsigned short*)(smem + 98304);
  unsigned short* const B2 = (unsigned short*)(smem + 114688);
  float* const red = (float*)smem;                               // 64KB, after main loop

  const int tid = threadIdx.x;
  const int lane = tid & 63;
  const int sk = tid >> 8;          // k-half 0..1
  const int wn = (tid >> 6) & 3;    // n-quarter 0..3
  const int m0 = blockIdx.x * 128;

  const int rl = lane & 15;
  const int kg = lane >> 4;

  // staging: thread t owns A chunks {t, t+512} (row t>>2, slot t&3, sk 0/1)
  // and B chunks {t, t+512, t+1024, t+1536}. Source slot pre-swizzled:
  // s_src = (t&3) ^ ((row>>1)&3) = (t&3) ^ ((t>>3)&3)  [row = t>>2]
  const int s_src = ((tid & 3) ^ ((tid >> 3) & 3)) * 8;   // element offset
  int gAa;                          // A pixel base addr (elements), slot folded
  {
    int m = m0 + (tid >> 2); if (m >= M_TOT) m = M_TOT - 1;
    int b = m / 3844; int rem = m - b * 3844;
    int h = rem / 62; int w = rem - h * 62;
    gAa = ((b * 64 + h) * 64 + w) * 256 + s_src;
  }
  const int fB0 = (tid >> 2) * 256 + s_src;            // B row base (elements)
  const int fB1 = ((tid >> 2) + 128) * 256 + s_src;    // row+128: same swizzle bits

  f32x4 zero = {0.f, 0.f, 0.f, 0.f};
  f32x4 acc[8][4];
#pragma unroll
  for (int i = 0; i < 8; ++i)
#pragma unroll
    for (int j = 0; j < 4; ++j) acc[i][j] = zero;

  // read-side: slot = kg ^ ((rl>>1)&3); row-repeats (+16) keep swizzle bits
  const int slotr = (kg ^ ((rl >> 1) & 3)) * 16;                    // bytes
  const int aoff = sk * 8192 + rl * 64 + slotr;                     // bytes
  const int boff = sk * 16384 + (wn * 64 + rl) * 64 + slotr;        // bytes

#define STAGE(t, bufA, bufB)                                                   \
  {                                                                            \
    int kk_ = (t) >> 2, cb_ = (t) & 3;                                         \
    int kh_ = kk_ / 3, kw_ = kk_ - kh_ * 3;                                    \
    int offA_ = kh_ * 16384 + kw_ * 256 + cb_ * 64;                            \
    int offB_ = kk_ * 65536 + cb_ * 64;                                        \
    gload16(xb + gAa + offA_,       &bufA[tid * 8]);                           \
    gload16(xb + gAa + offA_ + 32,  &bufA[(tid + 512) * 8]);                   \
    gload16(K2t + offB_ + fB0,      &bufB[tid * 8]);                           \
    gload16(K2t + offB_ + fB1,      &bufB[(tid + 512) * 8]);                   \
    gload16(K2t + offB_ + fB0 + 32, &bufB[(tid + 1024) * 8]);                  \
    gload16(K2t + offB_ + fB1 + 32, &bufB[(tid + 1536) * 8]);                  \
  }

#define STEP(t, cA, cB, nA, nB)                                                \
  {                                                                            \
    if ((t) == 35) asm volatile("s_waitcnt vmcnt(0)" ::: "memory");            \
    else           asm volatile("s_waitcnt vmcnt(6)" ::: "memory");            \
    __builtin_amdgcn_sched_barrier(0);                                         \
    __builtin_amdgcn_s_barrier();                                              \
    __builtin_amdgcn_sched_barrier(0);                                         \
    if ((t) < 34) { STAGE((t) + 2, nA, nB); }                                  \
    bf16x8 af[8], bfr[4];                                                      \
    _Pragma("unroll")                                                          \
    for (int mi = 0; mi < 8; ++mi)                                             \
      af[mi] = *(const bf16x8*)((const char*)(cA) + aoff + mi * 1024);         \
    _Pragma("unroll")                                                          \
    for (int ni = 0; ni < 4; ++ni)                                             \
      bfr[ni] = *(const bf16x8*)((const char*)(cB) + boff + ni * 1024);        \
    __builtin_amdgcn_s_setprio(1);                                             \
    _Pragma("unroll")                                                          \
    for (int mi = 0; mi < 8; ++mi)                                             \
      _Pragma("unroll")                                                        \
      for (int ni = 0; ni < 4; ++ni)                                           \
        acc[mi][ni] = __builtin_amdgcn_mfma_f32_16x16x32_bf16(                 \
            af[mi], bfr[ni], acc[mi][ni], 0, 0, 0);                            \
    __builtin_amdgcn_s_setprio(0);                                             \
  }

  STAGE(0, A0, B0);
  STAGE(1, A1, B1);

  for (int tt = 0; tt < 12; ++tt) {
    int t0 = tt * 3;
    STEP(t0,     A0, B0, A2, B2);
    STEP(t0 + 1, A1, B1, A0, B0);
    STEP(t0 + 2, A2, B2, A1, B1);
  }

  __syncthreads();   // main loop done; smem reused as reduction buffer

  // epilogue: sk=1 waves stage acc in LDS; sk=0 adds + stores.
  // D row = kg*4 + r (+16*mi), col = rl (+16*ni +64*wn).
#pragma unroll
  for (int round = 0; round < 2; ++round) {
    if (sk == 1) {
#pragma unroll
      for (int mc = 0; mc < 4; ++mc)
#pragma unroll
        for (int ni = 0; ni < 4; ++ni)
          *(f32x4*)((char*)red + (((wn * 4 + mc) * 4 + ni) * 64 + lane) * 16) =
              acc[round * 4 + mc][ni];
    }
    __syncthreads();
    if (sk == 0) {
#pragma unroll
      for (int mc = 0; mc < 4; ++mc) {
        int mi = round * 4 + mc;
        int mb = m0 + mi * 16 + kg * 4;
#pragma unroll
        for (int ni = 0; ni < 4; ++ni) {
          f32x4 o = *(f32x4*)((char*)red + (((wn * 4 + mc) * 4 + ni) * 64 + lane) * 16);
          o += acc[mi][ni];
          int f = wn * 64 + ni * 16 + rl;
#pragma unroll
          for (int r = 0; r < 4; ++r) {
            int m = mb + r;
            if (m < M_TOT) out[m * 256 + f] = o[r];
          }
        }
      }
    }
    __syncthreads();
  }
#undef STAGE
#undef STEP
}

extern "C" void kernel_launch(void* const* d_in, const int* in_sizes, int n_in,
                              void* d_out, int out_size, void* d_ws, size_t ws_size,
                              hipStream_t stream) {
  const float* x = (const float*)d_in[0];   // [8,64,64,256]
  const float* P = (const float*)d_in[1];   // [256,256]
  const float* Q = (const float*)d_in[2];   // [256,3,3,16]
  const float* S = (const float*)d_in[3];   // [256,16,256]
  float* out = (float*)d_out;               // [8,62,62,256]

  char* ws = (char*)d_ws;
  unsigned short* xb   = (unsigned short*)ws;                        // 16,777,216 B
  unsigned short* K2t  = (unsigned short*)(ws + 16777216);           //  1,179,648 B
  float*          Keff = (float*)(ws + 16777216 + 1179648);          //  2,359,296 B

  prep1<<<4096 + 256, 256, 0, stream>>>(x, Q, S, xb, Keff);
  k2t_k<<<576, 256, 0, stream>>>(P, Keff, K2t);
  conv_gemm<<<241, 512, 0, stream>>>(xb, K2t, out);
}